// Round 1
// baseline (1318.022 us; speedup 1.0000x reference)
//
#include <hip/hip_runtime.h>

#define NFEAT 128
#define NHID 64
#define NCLASS 40

// ---------------- degree / normalization ----------------

__global__ void deg_kernel(const int* __restrict__ dst, float* __restrict__ deg, int E) {
    int i = blockIdx.x * blockDim.x + threadIdx.x;
    if (i < E) atomicAdd(&deg[dst[i]], 1.0f);
}

__global__ void dinv_kernel(float* __restrict__ deg, int N) {
    int i = blockIdx.x * blockDim.x + threadIdx.x;
    if (i < N) deg[i] = rsqrtf(deg[i] + 1.0f);  // +1 = self loop; deg>=1 always
}

// ---------------- dense linear: out[n,j] = sum_k f(in[n,k]) * W[k,j] ----------------
// f = relu(x + bias) when RELU_BIAS (bias/relu belong to the PREVIOUS layer's epilogue,
// applied lazily on read). Block: 256 threads = 64(tx) x 4(ty); 16 nodes per block,
// 4 nodes per thread. W staged in LDS (reused by all 16 nodes).

template<int K, int F, bool RELU_BIAS>
__launch_bounds__(256)
__global__ void lin_kernel(const float* __restrict__ in, const float* __restrict__ W,
                           const float* __restrict__ bias, float* __restrict__ out, int N) {
    __shared__ float Ws[K * F];
    __shared__ float xs[16][K];
    const int tid = threadIdx.x;
    const int tx = tid & 63;
    const int ty = tid >> 6;
    const int n0 = blockIdx.x * 16;

    for (int idx = tid; idx < K * F; idx += 256) Ws[idx] = W[idx];
    for (int idx = tid; idx < 16 * K; idx += 256) {
        int ni = idx >> (K == 128 ? 7 : 6);   // K is a power of two (128 or 64)
        int k  = idx & (K - 1);
        int n  = n0 + ni;
        float v = (n < N) ? in[(size_t)n * K + k] : 0.0f;
        if constexpr (RELU_BIAS) v = fmaxf(v + bias[k], 0.0f);
        xs[ni][k] = v;
    }
    __syncthreads();

    if (tx < F) {
        float acc[4] = {0.0f, 0.0f, 0.0f, 0.0f};
        #pragma unroll 16
        for (int k = 0; k < K; ++k) {
            float w = Ws[k * F + tx];          // consecutive tx -> <=2 lanes/bank (free)
            #pragma unroll
            for (int i = 0; i < 4; ++i)
                acc[i] += xs[ty * 4 + i][k] * w;  // same addr across wave -> broadcast
        }
        #pragma unroll
        for (int i = 0; i < 4; ++i) {
            int n = n0 + ty * 4 + i;
            if (n < N) out[(size_t)n * F + tx] = acc[i];
        }
    }
}

// ---------------- aggregation ----------------
// Initialize agg buffer with the self-loop term (also replaces a memset):
//   a[n,j] = t[n,j] * dinv[n]^2
template<int F>
__global__ void selfloop_init(const float* __restrict__ t, const float* __restrict__ dinv,
                              float* __restrict__ a, int total) {
    int idx = blockIdx.x * blockDim.x + threadIdx.x;
    if (idx < total) {
        int n = idx / F;
        float di = dinv[n];
        a[idx] = t[idx] * (di * di);
    }
}

// One thread per (edge, feature). For F=64 a full wave = one edge's row:
// broadcast index loads, coalesced 256B gather, coalesced atomics.
template<int F>
__global__ void agg_kernel(const float* __restrict__ t, const float* __restrict__ dinv,
                           const int* __restrict__ src, const int* __restrict__ dst,
                           float* __restrict__ a, int total) {
    int idx = blockIdx.x * blockDim.x + threadIdx.x;
    if (idx >= total) return;
    int e = idx / F;
    int j = idx - e * F;
    int s = src[e];
    int d = dst[e];
    float w = dinv[s] * dinv[d];
    atomicAdd(&a[d * F + j], t[s * F + j] * w);
}

// ---------------- log_softmax over 40 classes, one wave per node ----------------
__global__ void lsm_kernel(const float* __restrict__ a, const float* __restrict__ b3,
                           float* __restrict__ out, int N) {
    int gid = blockIdx.x * blockDim.x + threadIdx.x;
    int n = gid >> 6;
    int lane = gid & 63;
    if (n >= N) return;
    float v = (lane < NCLASS) ? a[n * NCLASS + lane] + b3[lane] : -1e30f;
    float m = v;
    #pragma unroll
    for (int off = 32; off > 0; off >>= 1)
        m = fmaxf(m, __shfl_xor(m, off, 64));
    float e = (lane < NCLASS) ? expf(v - m) : 0.0f;
    float s = e;
    #pragma unroll
    for (int off = 32; off > 0; off >>= 1)
        s += __shfl_xor(s, off, 64);
    if (lane < NCLASS) out[n * NCLASS + lane] = v - m - logf(s);
}

// ---------------- launch ----------------

extern "C" void kernel_launch(void* const* d_in, const int* in_sizes, int n_in,
                              void* d_out, int out_size, void* d_ws, size_t ws_size,
                              hipStream_t stream) {
    const float* x  = (const float*)d_in[0];
    const int*   ei = (const int*)  d_in[1];
    const float* W1 = (const float*)d_in[2];
    const float* b1 = (const float*)d_in[3];
    const float* W2 = (const float*)d_in[4];
    const float* b2 = (const float*)d_in[5];
    const float* W3 = (const float*)d_in[6];
    const float* b3 = (const float*)d_in[7];
    const int N = in_sizes[0] / NFEAT;
    const int E = in_sizes[1] / 2;
    const int* src = ei;
    const int* dst = ei + E;
    float* out = (float*)d_out;

    // workspace: dinv (N, aligned up), tbuf (N*64), abuf (N*64) ~ 51.6 MB
    float* dinv = (float*)d_ws;
    float* tbuf = dinv + (((size_t)N + 255) & ~(size_t)255);
    float* abuf = tbuf + (size_t)N * NHID;

    hipMemsetAsync(dinv, 0, (size_t)N * sizeof(float), stream);
    deg_kernel<<<(E + 255) / 256, 256, 0, stream>>>(dst, dinv, E);
    dinv_kernel<<<(N + 255) / 256, 256, 0, stream>>>(dinv, N);

    const int linBlocks = (N + 15) / 16;

    // ---- layer 1: h1 = x @ W1 ; a1 = Ahat h1 ----
    lin_kernel<NFEAT, NHID, false><<<linBlocks, 256, 0, stream>>>(x, W1, nullptr, tbuf, N);
    selfloop_init<NHID><<<(N * NHID + 255) / 256, 256, 0, stream>>>(tbuf, dinv, abuf, N * NHID);
    agg_kernel<NHID><<<(E * NHID + 255) / 256, 256, 0, stream>>>(tbuf, dinv, src, dst, abuf, E * NHID);

    // ---- layer 2: h2 = relu(a1 + b1) @ W2 ; a2 = Ahat h2 ----
    lin_kernel<NHID, NHID, true><<<linBlocks, 256, 0, stream>>>(abuf, W2, b1, tbuf, N);
    selfloop_init<NHID><<<(N * NHID + 255) / 256, 256, 0, stream>>>(tbuf, dinv, abuf, N * NHID);
    agg_kernel<NHID><<<(E * NHID + 255) / 256, 256, 0, stream>>>(tbuf, dinv, src, dst, abuf, E * NHID);

    // ---- layer 3: h3 = relu(a2 + b2) @ W3 ; a3 = Ahat h3 ----
    lin_kernel<NHID, NCLASS, true><<<linBlocks, 256, 0, stream>>>(abuf, W3, b2, tbuf, N);
    selfloop_init<NCLASS><<<(N * NCLASS + 255) / 256, 256, 0, stream>>>(tbuf, dinv, abuf, N * NCLASS);
    agg_kernel<NCLASS><<<(E * NCLASS + 255) / 256, 256, 0, stream>>>(tbuf, dinv, src, dst, abuf, E * NCLASS);

    // ---- log_softmax(a3 + b3) ----
    lsm_kernel<<<((size_t)N * 64 + 255) / 256, 256, 0, stream>>>(abuf, b3, out, N);
}

// Round 2
// 588.846 us; speedup vs baseline: 2.2383x; 2.2383x over previous
//
#include <hip/hip_runtime.h>

#define NFEAT 128
#define NHID 64
#define NCLASS 40

// ======================= degree / normalization =======================

__global__ void deg_kernel(const int* __restrict__ dst, int* __restrict__ deg, int E) {
    int i = blockIdx.x * blockDim.x + threadIdx.x;
    if (i < E) atomicAdd(&deg[dst[i]], 1);
}

__global__ void dinv_kernel(const int* __restrict__ deg, float* __restrict__ dinv, int N) {
    int i = blockIdx.x * blockDim.x + threadIdx.x;
    if (i < N) dinv[i] = rsqrtf((float)deg[i] + 1.0f);  // +1 self loop
}

// ======================= exclusive scan (CSR row_ptr) =======================
// chunk = 1024 elements per block (256 thr x 4)

__global__ void scan_block_sums(const int* __restrict__ deg, int* __restrict__ bsums, int N) {
    __shared__ int sd[256];
    int t = threadIdx.x;
    int base = blockIdx.x * 1024 + t * 4;
    int s = 0;
    #pragma unroll
    for (int i = 0; i < 4; ++i) { int idx = base + i; if (idx < N) s += deg[idx]; }
    sd[t] = s; __syncthreads();
    for (int off = 128; off > 0; off >>= 1) {
        if (t < off) sd[t] += sd[t + off];
        __syncthreads();
    }
    if (t == 0) bsums[blockIdx.x] = sd[0];
}

__global__ void scan_bsums(int* __restrict__ bsums, int nb, int* __restrict__ row_ptr,
                           int N, int E) {
    __shared__ int sd[256];
    int t = threadIdx.x;
    sd[t] = (t < nb) ? bsums[t] : 0;
    __syncthreads();
    for (int off = 1; off < 256; off <<= 1) {
        int v = (t >= off) ? sd[t - off] : 0;
        __syncthreads();
        sd[t] += v;
        __syncthreads();
    }
    if (t < nb) bsums[t] = (t == 0) ? 0 : sd[t - 1];   // exclusive
    if (t == 0) row_ptr[N] = E;
}

__global__ void scan_final(const int* __restrict__ deg, const int* __restrict__ bsums,
                           int* __restrict__ row_ptr, int* __restrict__ cursor, int N) {
    __shared__ int sd[256];
    int t = threadIdx.x;
    int base = blockIdx.x * 1024 + t * 4;
    int local[4];
    int s = 0;
    #pragma unroll
    for (int i = 0; i < 4; ++i) {
        local[i] = s;
        int idx = base + i;
        s += (idx < N) ? deg[idx] : 0;
    }
    sd[t] = s; __syncthreads();
    for (int off = 1; off < 256; off <<= 1) {
        int v = (t >= off) ? sd[t - off] : 0;
        __syncthreads();
        sd[t] += v;
        __syncthreads();
    }
    int toff = (t == 0) ? 0 : sd[t - 1];
    int boff = bsums[blockIdx.x];
    #pragma unroll
    for (int i = 0; i < 4; ++i) {
        int idx = base + i;
        if (idx < N) {
            int v = boff + toff + local[i];
            row_ptr[idx] = v;
            cursor[idx] = v;
        }
    }
}

__global__ void scatter_kernel(const int* __restrict__ src, const int* __restrict__ dst,
                               int* __restrict__ cursor, int* __restrict__ csr_src, int E) {
    int i = blockIdx.x * blockDim.x + threadIdx.x;
    if (i < E) {
        int pos = atomicAdd(&cursor[dst[i]], 1);
        csr_src[pos] = src[i];
    }
}

// ======================= dense linear =======================
// out[n,:] = dinv[n] * (f(in[n,:]) @ W), f = relu(x + bias_prev) if RELU_BIAS.
// 256 threads; FT=F/4 feature-quads per node; each thread owns NPT=4 nodes ->
// per kq: 4x b128 W reads reused across 4 nodes (register blocking), ~0.31
// LDS instrs per FMA instead of 1.25 in the v1 kernel.

template<int K, int F, bool RELU_BIAS>
__launch_bounds__(256)
__global__ void lin_kernel(const float* __restrict__ in, const float* __restrict__ W,
                           const float* __restrict__ bias, const float* __restrict__ dinv,
                           float* __restrict__ out, int N) {
    constexpr int FT = F / 4;            // 16 (F=64) or 10 (F=40)
    constexpr int TG = 256 / FT;         // 16 or 25 node-groups
    constexpr int NPT = 4;               // nodes per thread
    constexpr int NODES = TG * NPT;      // 64 or 100 nodes per block
    constexpr int KP = K + 4;            // padded x row (keeps 16B align, kills bank conflicts)

    __shared__ alignas(16) float Ws[K * F];
    __shared__ alignas(16) float xs[NODES * KP];

    const int tid = threadIdx.x;
    const int n0 = blockIdx.x * NODES;

    for (int q = tid; q < K * F / 4; q += 256)
        ((float4*)Ws)[q] = ((const float4*)W)[q];

    for (int q = tid; q < NODES * (K / 4); q += 256) {
        int ni = q / (K / 4);
        int kq = q - ni * (K / 4);
        int n = n0 + ni;
        float4 v = make_float4(0.f, 0.f, 0.f, 0.f);
        if (n < N) v = ((const float4*)in)[(size_t)n * (K / 4) + kq];
        if constexpr (RELU_BIAS) {
            float4 b = ((const float4*)bias)[kq];
            v.x = fmaxf(v.x + b.x, 0.f);
            v.y = fmaxf(v.y + b.y, 0.f);
            v.z = fmaxf(v.z + b.z, 0.f);
            v.w = fmaxf(v.w + b.w, 0.f);
        }
        *(float4*)&xs[ni * KP + kq * 4] = v;
    }
    __syncthreads();

    const int tx = tid % FT;
    const int tg = tid / FT;
    if (tg >= TG) return;                // F=40: threads 250..255 idle after staging

    float4 acc[NPT];
    #pragma unroll
    for (int i = 0; i < NPT; ++i) acc[i] = make_float4(0.f, 0.f, 0.f, 0.f);

    #pragma unroll 4
    for (int kq = 0; kq < K / 4; ++kq) {
        float4 w0 = *(const float4*)&Ws[(kq * 4 + 0) * F + tx * 4];
        float4 w1 = *(const float4*)&Ws[(kq * 4 + 1) * F + tx * 4];
        float4 w2 = *(const float4*)&Ws[(kq * 4 + 2) * F + tx * 4];
        float4 w3 = *(const float4*)&Ws[(kq * 4 + 3) * F + tx * 4];
        #pragma unroll
        for (int i = 0; i < NPT; ++i) {
            float4 xv = *(const float4*)&xs[(tg * NPT + i) * KP + kq * 4];
            acc[i].x += xv.x * w0.x + xv.y * w1.x + xv.z * w2.x + xv.w * w3.x;
            acc[i].y += xv.x * w0.y + xv.y * w1.y + xv.z * w2.y + xv.w * w3.y;
            acc[i].z += xv.x * w0.z + xv.y * w1.z + xv.z * w2.z + xv.w * w3.z;
            acc[i].w += xv.x * w0.w + xv.y * w1.w + xv.z * w2.w + xv.w * w3.w;
        }
    }

    #pragma unroll
    for (int i = 0; i < NPT; ++i) {
        int n = n0 + tg * NPT + i;
        if (n < N) {
            float d = dinv[n];
            float4 r = make_float4(acc[i].x * d, acc[i].y * d, acc[i].z * d, acc[i].w * d);
            *(float4*)&out[(size_t)n * F + tx * 4] = r;
        }
    }
}

// ======================= gather aggregation (no atomics) =======================
// out[d,:] = dinv[d] * ( g[d,:] + sum_{s in N(d)} g[s,:] ), one wave per node,
// 4-deep pipelined neighbor loads.

template<int F>
__launch_bounds__(256)
__global__ void gather_kernel(const float* __restrict__ g, const float* __restrict__ dinv,
                              const int* __restrict__ row_ptr, const int* __restrict__ csr_src,
                              float* __restrict__ out, int N) {
    int gid = blockIdx.x * blockDim.x + threadIdx.x;
    int n = gid >> 6;
    int lane = gid & 63;
    if (n >= N) return;
    int e0 = row_ptr[n], e1 = row_ptr[n + 1];
    float acc = (lane < F) ? g[(size_t)n * F + lane] : 0.f;   // self loop
    int e = e0;
    for (; e + 4 <= e1; e += 4) {
        int s0 = csr_src[e + 0];
        int s1 = csr_src[e + 1];
        int s2 = csr_src[e + 2];
        int s3 = csr_src[e + 3];
        float v0 = 0.f, v1 = 0.f, v2 = 0.f, v3 = 0.f;
        if (lane < F) {
            v0 = g[(size_t)s0 * F + lane];
            v1 = g[(size_t)s1 * F + lane];
            v2 = g[(size_t)s2 * F + lane];
            v3 = g[(size_t)s3 * F + lane];
        }
        acc += (v0 + v1) + (v2 + v3);
    }
    for (; e < e1; ++e) {
        int s = csr_src[e];
        if (lane < F) acc += g[(size_t)s * F + lane];
    }
    if (lane < F) out[(size_t)n * F + lane] = dinv[n] * acc;
}

// ======================= log_softmax (40 classes, one wave/node) =======================

__global__ void lsm_kernel(const float* __restrict__ a, const float* __restrict__ b3,
                           float* __restrict__ out, int N) {
    int gid = blockIdx.x * blockDim.x + threadIdx.x;
    int n = gid >> 6;
    int lane = gid & 63;
    if (n >= N) return;
    float v = (lane < NCLASS) ? a[(size_t)n * NCLASS + lane] + b3[lane] : -1e30f;
    float m = v;
    #pragma unroll
    for (int off = 32; off > 0; off >>= 1)
        m = fmaxf(m, __shfl_xor(m, off, 64));
    float e = (lane < NCLASS) ? expf(v - m) : 0.f;
    float s = e;
    #pragma unroll
    for (int off = 32; off > 0; off >>= 1)
        s += __shfl_xor(s, off, 64);
    if (lane < NCLASS) out[(size_t)n * NCLASS + lane] = v - m - logf(s);
}

// ======================= launch =======================

extern "C" void kernel_launch(void* const* d_in, const int* in_sizes, int n_in,
                              void* d_out, int out_size, void* d_ws, size_t ws_size,
                              hipStream_t stream) {
    const float* x  = (const float*)d_in[0];
    const int*   ei = (const int*)  d_in[1];
    const float* W1 = (const float*)d_in[2];
    const float* b1 = (const float*)d_in[3];
    const float* W2 = (const float*)d_in[4];
    const float* b2 = (const float*)d_in[5];
    const float* W3 = (const float*)d_in[6];
    const float* b3 = (const float*)d_in[7];
    const int N = in_sizes[0] / NFEAT;
    const int E = in_sizes[1] / 2;
    const int* src = ei;
    const int* dst = ei + E;
    float* out = (float*)d_out;

    // ---- workspace layout (4-byte units) ----
    const size_t Np = ((size_t)N + 256) & ~(size_t)255;   // >= N+1, 256-aligned
    const size_t Ep = ((size_t)E + 255) & ~(size_t)255;
    float* base = (float*)d_ws;
    int*   deg     = (int*)(base);                  // N
    float* dinv    = base + Np;                     // N
    int*   row_ptr = (int*)(base + 2 * Np);         // N+1
    int*   cursor  = (int*)(base + 3 * Np);         // N
    int*   bsums   = (int*)(base + 4 * Np);         // 256
    int*   csr_src = (int*)(base + 4 * Np + 256);   // E
    float* tbuf    = base + 4 * Np + 256 + Ep;      // N*64
    float* abuf    = tbuf + (size_t)N * NHID;       // N*64
    // total ~ 59.3 MB

    const int NBLK = (N + 1023) / 1024;             // scan chunks (98)

    // ---- CSR build ----
    hipMemsetAsync(deg, 0, (size_t)N * sizeof(int), stream);
    deg_kernel<<<(E + 255) / 256, 256, 0, stream>>>(dst, deg, E);
    dinv_kernel<<<(N + 255) / 256, 256, 0, stream>>>(deg, dinv, N);
    scan_block_sums<<<NBLK, 256, 0, stream>>>(deg, bsums, N);
    scan_bsums<<<1, 256, 0, stream>>>(bsums, NBLK, row_ptr, N, E);
    scan_final<<<NBLK, 256, 0, stream>>>(deg, bsums, row_ptr, cursor, N);
    scatter_kernel<<<(E + 255) / 256, 256, 0, stream>>>(src, dst, cursor, csr_src, E);

    const int gatherBlocks = (N * 64 + 255) / 256;

    // ---- layer 1 ----
    lin_kernel<NFEAT, NHID, false><<<(N + 63) / 64, 256, 0, stream>>>(x, W1, nullptr, dinv, tbuf, N);
    gather_kernel<NHID><<<gatherBlocks, 256, 0, stream>>>(tbuf, dinv, row_ptr, csr_src, abuf, N);

    // ---- layer 2 ----
    lin_kernel<NHID, NHID, true><<<(N + 63) / 64, 256, 0, stream>>>(abuf, W2, b1, dinv, tbuf, N);
    gather_kernel<NHID><<<gatherBlocks, 256, 0, stream>>>(tbuf, dinv, row_ptr, csr_src, abuf, N);

    // ---- layer 3 ----
    lin_kernel<NHID, NCLASS, true><<<(N + 99) / 100, 256, 0, stream>>>(abuf, W3, b2, dinv, tbuf, N);
    gather_kernel<NCLASS><<<gatherBlocks, 256, 0, stream>>>(tbuf, dinv, row_ptr, csr_src, abuf, N);

    // ---- log_softmax ----
    lsm_kernel<<<gatherBlocks, 256, 0, stream>>>(abuf, b3, out, N);
}